// Round 10
// baseline (60.873 us; speedup 1.0000x reference)
//
#include <hip/hip_runtime.h>
#include <hip/hip_bf16.h>
#include <math.h>

// Problem: B=64, C=128, H=64, W=64, HW=4096
// out   : (B,C,H,W) f32 at d_out[0];  logdet: (B,) f32 at d_out[33554432]
//
// Algebra: pool[b,l] = sum_c wbar[c]*mask[c,l]*x[b,c,l] + bbar,
//   wbar[c] = mean_o w[o,c], bbar = mean(bias)  -> 128x128 mix never built.
// logdet[b] = 64 * sum_l log g[b,l] + B*(HW/2)*sum_c log s_sig[c]
//
// Round-10: BARRIER-FREE main. lane = (cg 0..15, jq 0..3): each wave owns
// all 128 channels x 16 pixels, pool reduction is 4x shfl_xor in-wave,
// zero __syncthreads -- stores issue as soon as the wave's own gate is
// ready (round-3/9 coupled a 32KB load burst to a 32KB store burst via a
// block barrier). Tradeoff: 16x64B segments per memory instruction
// instead of 4x256B (identical line traffic). prep = round-9's.

#define EPS 1e-5f
#define NC 128
#define NHW 4096
#define NB 64
#define LT 64             // pixels per block tile (4 waves x 16 pixels)
#define NLT (NHW / LT)    // 64
#define NPART (NLT * 4)   // per-wave partials per batch = 256

typedef __attribute__((ext_vector_type(4))) float f4;

// ws layout (floats): [0..127] wbar, [128..255] s_sig, [256] bbar,
//                     [257] logdet const, [512..512+NB*NPART) partials

__global__ __launch_bounds__(256) void prep_kernel(const float* __restrict__ w,
                                                   const float* __restrict__ bias,
                                                   const float* __restrict__ s,
                                                   float* __restrict__ ws) {
    __shared__ float wred[8][NC];   // [o-range][c] partial column sums
    __shared__ float lw[4], bw[4];

    const int tid = threadIdx.x;    // 256 threads
    const int q   = tid & 31;       // c-quad (4 channels)
    const int r   = tid >> 5;       // o-range 0..7 (16 rows each)

    {
        const float* __restrict__ wp = w + (size_t)(r * 16) * NC + q * 4;
        float4 a = make_float4(0.f, 0.f, 0.f, 0.f);
#pragma unroll
        for (int o = 0; o < 16; ++o) {
            const float4 v = *reinterpret_cast<const float4*>(wp + (size_t)o * NC);
            a.x += v.x; a.y += v.y; a.z += v.z; a.w += v.w;
        }
        *reinterpret_cast<float4*>(&wred[r][q * 4]) = a;
    }
    __syncthreads();

    float lv = 0.f, bv = 0.f;
    if (tid < NC) {
        float sum = 0.f;
#pragma unroll
        for (int rr = 0; rr < 8; ++rr) sum += wred[rr][tid];
        ws[tid] = sum * (1.f / NC);                    // wbar
        const float ssig = 1.f / (1.f + __expf(-s[tid])) + EPS;
        ws[NC + tid] = ssig;                           // s_sig
        lv = __logf(ssig);
        bv = bias[tid];
    }
#pragma unroll
    for (int off = 32; off > 0; off >>= 1) {
        lv += __shfl_down(lv, off);
        bv += __shfl_down(bv, off);
    }
    const int wave = tid >> 6;
    if ((tid & 63) == 0) { lw[wave] = lv; bw[wave] = bv; }
    __syncthreads();
    if (tid == 0) {
        const float sl = lw[0] + lw[1] + lw[2] + lw[3];
        const float sb = bw[0] + bw[1] + bw[2] + bw[3];
        ws[256] = sb * (1.f / NC);                     // bbar
        ws[257] = (float)NB * (float)(NHW / 2) * sl;   // logdet const
    }
}

__global__ __launch_bounds__(256) void main_kernel(const float* __restrict__ x,
                                                   const float* __restrict__ ws,
                                                   const float* __restrict__ offp,
                                                   float* __restrict__ out,
                                                   float* __restrict__ partials) {
    const int tid  = threadIdx.x;
    const int lane = tid & 63;
    const int wave = tid >> 6;      // 0..3
    const int jq   = lane & 3;      // pixel quad within wave's 16 pixels
    const int cg   = lane >> 2;     // channel group 0..15 (8 channels each)

    const int lt = blockIdx.x;      // l-tile 0..63
    const int b  = blockIdx.y;      // batch
    const int l0 = lt * LT + wave * 16;   // wave's 16-pixel base (mult of 16)

    const size_t base = (size_t)b * (NC * NHW) + (size_t)(cg * 8) * NHW + l0 + jq * 4;
    const float* __restrict__ xp = x + base;

    // ---- load 8 float4 into registers (16x64B segments per instr) ----
    float4 v[8];
#pragma unroll
    for (int k = 0; k < 8; ++k)
        v[k] = *reinterpret_cast<const float4*>(xp + (size_t)k * NHW);

    // ---- per-thread pool partial over its 8 channels ----
    // pixel p = l0 + jq*4 + e; parity (c+p)&1 = (c+e)&1 (l0, jq*4 even)
    float4 acc = make_float4(0.f, 0.f, 0.f, 0.f);
#pragma unroll
    for (int k = 0; k < 8; ++k) {
        const int c = cg * 8 + k;
        const float wb = ws[c];
        if (c & 1) { acc.x += wb * v[k].x; acc.z += wb * v[k].z; }
        else       { acc.y += wb * v[k].y; acc.w += wb * v[k].w; }
    }

    // ---- in-wave reduction over the 16 channel-groups (lane bits 2..5) ----
#pragma unroll
    for (int off = 4; off <= 32; off <<= 1) {
        acc.x += __shfl_xor(acc.x, off);
        acc.y += __shfl_xor(acc.y, off);
        acc.z += __shfl_xor(acc.z, off);
        acc.w += __shfl_xor(acc.w, off);
    }

    // ---- gate for this lane's pixel quad (no barrier anywhere) ----
    const float cst = ws[256] + offp[0];
    float4 g;
    g.x = 1.f / (1.f + __expf(-(acc.x + cst))) + EPS;
    g.y = 1.f / (1.f + __expf(-(acc.y + cst))) + EPS;
    g.z = 1.f / (1.f + __expf(-(acc.z + cst))) + EPS;
    g.w = 1.f / (1.f + __expf(-(acc.w + cst))) + EPS;

    // ---- logdet: per-wave partial (sum over the wave's 16 pixels) ----
    {
        float slg = (lane < 4)
                  ? (__logf(g.x) + __logf(g.y) + __logf(g.z) + __logf(g.w))
                  : 0.f;
        slg += __shfl_down(slg, 2);
        slg += __shfl_down(slg, 1);
        if (lane == 0) partials[b * NPART + lt * 4 + wave] = slg;
    }

    // ---- scale registers and store (non-temporal: write-once stream) ----
    const float* __restrict__ ssig = ws + NC;
    float* __restrict__ op = out + base;
#pragma unroll
    for (int k = 0; k < 8; ++k) {
        const int c = cg * 8 + k;
        const float sc = ssig[c];
        f4 o;
        if (c & 1) { o.x = v[k].x * sc;  o.y = v[k].y * g.y;
                     o.z = v[k].z * sc;  o.w = v[k].w * g.w; }
        else       { o.x = v[k].x * g.x; o.y = v[k].y * sc;
                     o.z = v[k].z * g.z; o.w = v[k].w * sc; }
        __builtin_nontemporal_store(o, reinterpret_cast<f4*>(op + (size_t)k * NHW));
    }
}

__global__ __launch_bounds__(64) void fin_kernel(const float* __restrict__ partials,
                                                 const float* __restrict__ ws,
                                                 float* __restrict__ logdet) {
    const int b = blockIdx.x;
    const int t = threadIdx.x;  // 64 threads; 256 partials per batch
    const float* __restrict__ pb = partials + b * NPART;
    float v = pb[t] + pb[t + 64] + pb[t + 128] + pb[t + 192];
#pragma unroll
    for (int off = 32; off > 0; off >>= 1) v += __shfl_down(v, off);
    if (t == 0) logdet[b] = 64.f * v + ws[257];  // (C//2) = 64
}

extern "C" void kernel_launch(void* const* d_in, const int* in_sizes, int n_in,
                              void* d_out, int out_size, void* d_ws, size_t ws_size,
                              hipStream_t stream) {
    const float* x    = (const float*)d_in[0];
    const float* w    = (const float*)d_in[1];
    const float* bias = (const float*)d_in[2];
    const float* s    = (const float*)d_in[3];
    const float* offp = (const float*)d_in[4];

    float* out    = (float*)d_out;
    float* logdet = out + (size_t)NB * NC * NHW;
    float* ws     = (float*)d_ws;
    float* partials = ws + 512;

    prep_kernel<<<1, 256, 0, stream>>>(w, bias, s, ws);
    main_kernel<<<dim3(NLT, NB), 256, 0, stream>>>(x, ws, offp, out, partials);
    fin_kernel<<<NB, 64, 0, stream>>>(partials, ws, logdet);
}

// Round 11
// 51.091 us; speedup vs baseline: 1.1915x; 1.1915x over previous
//
#include <hip/hip_runtime.h>
#include <hip/hip_bf16.h>
#include <math.h>

// Problem: B=64, C=128, H=64, W=64, HW=4096
// out   : (B,C,H,W) f32 at d_out[0];  logdet: (B,) f32 at d_out[33554432]
//
// Algebra: pool[b,l] = sum_c wbar[c]*mask[c,l]*x[b,c,l] + bbar,
//   wbar[c] = mean_o w[o,c], bbar = mean(bias)  -> 128x128 mix never built.
// logdet[b] = 64 * sum_l log g[b,l] + B*(HW/2)*sum_c log s_sig[c]
//
// FINAL (= round-9, best measured 51.0us ~ 89% of copy ceiling):
// 3 kernels: latency-optimal prep (1 block), streaming main (x in regs,
// 4x256B segments/instr, one barrier, nt stores), tiny fin. Measured
// alternatives that all regressed: fused single kernel (+9us), contended
// atomics (+7), last-block coherence finalize (+140), 1KiB-contig 1024thr
// (+8), barrier-free 64B segments (+10, 25% write amplification).

#define EPS 1e-5f
#define NC 128
#define NHW 4096
#define NB 64
#define LT 64            // pixels per block tile
#define NLT (NHW / LT)   // 64

typedef __attribute__((ext_vector_type(4))) float f4;

// ws layout (floats): [0..127] wbar, [128..255] s_sig, [256] bbar,
//                     [257] logdet const, [512..512+NB*NLT) partials

__global__ __launch_bounds__(256) void prep_kernel(const float* __restrict__ w,
                                                   const float* __restrict__ bias,
                                                   const float* __restrict__ s,
                                                   float* __restrict__ ws) {
    __shared__ float wred[8][NC];   // [o-range][c] partial column sums
    __shared__ float lw[4], bw[4];

    const int tid = threadIdx.x;    // 256 threads
    const int q   = tid & 31;       // c-quad (4 channels)
    const int r   = tid >> 5;       // o-range 0..7 (16 rows each)

    // ---- 16 independent coalesced float4 loads; single memory round-trip ----
    {
        const float* __restrict__ wp = w + (size_t)(r * 16) * NC + q * 4;
        float4 a = make_float4(0.f, 0.f, 0.f, 0.f);
#pragma unroll
        for (int o = 0; o < 16; ++o) {
            const float4 v = *reinterpret_cast<const float4*>(wp + (size_t)o * NC);
            a.x += v.x; a.y += v.y; a.z += v.z; a.w += v.w;
        }
        *reinterpret_cast<float4*>(&wred[r][q * 4]) = a;
    }
    __syncthreads();

    // ---- finalize per-channel params; shuffle-reduce bias & log s_sig ----
    float lv = 0.f, bv = 0.f;
    if (tid < NC) {
        float sum = 0.f;
#pragma unroll
        for (int rr = 0; rr < 8; ++rr) sum += wred[rr][tid];
        ws[tid] = sum * (1.f / NC);                    // wbar
        const float ssig = 1.f / (1.f + __expf(-s[tid])) + EPS;
        ws[NC + tid] = ssig;                           // s_sig
        lv = __logf(ssig);
        bv = bias[tid];
    }
#pragma unroll
    for (int off = 32; off > 0; off >>= 1) {
        lv += __shfl_down(lv, off);
        bv += __shfl_down(bv, off);
    }
    const int wave = tid >> 6;
    if ((tid & 63) == 0) { lw[wave] = lv; bw[wave] = bv; }
    __syncthreads();
    if (tid == 0) {
        const float sl = lw[0] + lw[1] + lw[2] + lw[3];
        const float sb = bw[0] + bw[1] + bw[2] + bw[3];
        ws[256] = sb * (1.f / NC);                     // bbar
        ws[257] = (float)NB * (float)(NHW / 2) * sl;   // logdet const
    }
}

__global__ __launch_bounds__(256) void main_kernel(const float* __restrict__ x,
                                                   const float* __restrict__ ws,
                                                   const float* __restrict__ offp,
                                                   float* __restrict__ out,
                                                   float* __restrict__ partials) {
    __shared__ float4 pp[4][16];   // 1 KiB: per-wave pool partials

    const int tid  = threadIdx.x;
    const int j    = tid & 15;     // pixel-quad index: pixels l0 + 4j .. 4j+3
    const int cg   = tid >> 4;     // channel group 0..15 (8 channels each)
    const int wave = tid >> 6;
    const int lane = tid & 63;

    const int lt = blockIdx.x;     // l-tile 0..63
    const int b  = blockIdx.y;     // batch
    const int l0 = lt * LT;        // multiple of 64 (even)

    const size_t base = (size_t)b * (NC * NHW) + (size_t)(cg * 8) * NHW + l0 + j * 4;
    const float* __restrict__ xp = x + base;

    // ---- load 8 float4 into registers ----
    float4 v[8];
#pragma unroll
    for (int k = 0; k < 8; ++k)
        v[k] = *reinterpret_cast<const float4*>(xp + (size_t)k * NHW);

    // ---- per-thread pool partial over its 8 channels ----
    float4 acc = make_float4(0.f, 0.f, 0.f, 0.f);
#pragma unroll
    for (int k = 0; k < 8; ++k) {
        const int c = cg * 8 + k;
        const float wb = ws[c];
        if (c & 1) { acc.x += wb * v[k].x; acc.z += wb * v[k].z; }
        else       { acc.y += wb * v[k].y; acc.w += wb * v[k].w; }
    }

    // ---- reduce over the 4 channel-groups within this wave ----
#pragma unroll
    for (int off = 16; off <= 32; off <<= 1) {
        acc.x += __shfl_xor(acc.x, off);
        acc.y += __shfl_xor(acc.y, off);
        acc.z += __shfl_xor(acc.z, off);
        acc.w += __shfl_xor(acc.w, off);
    }
    if (lane < 16) pp[wave][j] = acc;   // lane==j for lane<16
    __syncthreads();

    // ---- final pool + gate (redundant per thread; VALU is idle) ----
    const float4 p0 = pp[0][j], p1 = pp[1][j], p2 = pp[2][j], p3 = pp[3][j];
    const float cst = ws[256] + offp[0];
    float4 g;
    g.x = 1.f / (1.f + __expf(-(p0.x + p1.x + p2.x + p3.x + cst))) + EPS;
    g.y = 1.f / (1.f + __expf(-(p0.y + p1.y + p2.y + p3.y + cst))) + EPS;
    g.z = 1.f / (1.f + __expf(-(p0.z + p1.z + p2.z + p3.z + cst))) + EPS;
    g.w = 1.f / (1.f + __expf(-(p0.w + p1.w + p2.w + p3.w + cst))) + EPS;

    // ---- logdet: per-block sum of log(g) (wave 0) ----
    if (wave == 0) {
        float slg = (lane < 16)
                  ? (__logf(g.x) + __logf(g.y) + __logf(g.z) + __logf(g.w))
                  : 0.f;
#pragma unroll
        for (int off = 32; off > 0; off >>= 1) slg += __shfl_down(slg, off);
        if (lane == 0) partials[b * gridDim.x + lt] = slg;
    }

    // ---- scale registers and store (non-temporal: write-once stream) ----
    const float* __restrict__ ssig = ws + NC;
    float* __restrict__ op = out + base;
#pragma unroll
    for (int k = 0; k < 8; ++k) {
        const int c = cg * 8 + k;
        const float sc = ssig[c];
        f4 o;
        if (c & 1) { o.x = v[k].x * sc;  o.y = v[k].y * g.y;
                     o.z = v[k].z * sc;  o.w = v[k].w * g.w; }
        else       { o.x = v[k].x * g.x; o.y = v[k].y * sc;
                     o.z = v[k].z * g.z; o.w = v[k].w * sc; }
        __builtin_nontemporal_store(o, reinterpret_cast<f4*>(op + (size_t)k * NHW));
    }
}

__global__ __launch_bounds__(64) void fin_kernel(const float* __restrict__ partials,
                                                 const float* __restrict__ ws,
                                                 float* __restrict__ logdet,
                                                 int nlt) {
    const int b = blockIdx.x;
    const int t = threadIdx.x;  // 64 threads
    float v = (t < nlt) ? partials[b * nlt + t] : 0.f;
#pragma unroll
    for (int off = 32; off > 0; off >>= 1) v += __shfl_down(v, off);
    if (t == 0) logdet[b] = 64.f * v + ws[257];  // (C//2) = 64
}

extern "C" void kernel_launch(void* const* d_in, const int* in_sizes, int n_in,
                              void* d_out, int out_size, void* d_ws, size_t ws_size,
                              hipStream_t stream) {
    const float* x    = (const float*)d_in[0];
    const float* w    = (const float*)d_in[1];
    const float* bias = (const float*)d_in[2];
    const float* s    = (const float*)d_in[3];
    const float* offp = (const float*)d_in[4];

    float* out    = (float*)d_out;
    float* logdet = out + (size_t)NB * NC * NHW;
    float* ws     = (float*)d_ws;
    float* partials = ws + 512;

    prep_kernel<<<1, 256, 0, stream>>>(w, bias, s, ws);
    main_kernel<<<dim3(NLT, NB), 256, 0, stream>>>(x, ws, offp, out, partials);
    fin_kernel<<<NB, 64, 0, stream>>>(partials, ws, logdet, NLT);
}